// Round 9
// baseline (348.882 us; speedup 1.0000x reference)
//
#include <hip/hip_runtime.h>
#include <cstdint>
#include <cstddef>

typedef unsigned short ushort_t;
typedef __attribute__((ext_vector_type(8))) short bf16x8;
typedef __attribute__((ext_vector_type(4))) float f32x4;

// Problem constants
#define PN1   10000
#define PN2   10000
#define NH    8
#define NLAY  2
#define NE12  320000
#define NE21  320000
#define NEF   500000
#define DL    10016   // padded per-node array stride
#define NBIN  8       // edge_dot m-bins (one per XCD)
#define BINW  1250    // m rows per bin
#define BCF   65536   // capacity per edge_dot bin (expected ~62.5K)
#define DCH   256     // chunks per part in edge_dot_part
#define NB2   20      // CSR dst-range bins per graph (width 512)
#define BC2   20480   // capacity per CSR bin (expected <=16384)
#define SRB   20      // src buckets per dst (width 512) for drift-aligned gathers

// ---------- bf16 helpers (RNE) ----------
__device__ __forceinline__ unsigned f2bf(float f) {
  union { float f; unsigned u; } v; v.f = f;
  return (v.u + 0x7FFFu + ((v.u >> 16) & 1u)) >> 16;
}
__device__ __forceinline__ float bf2f(unsigned s) {
  union { float f; unsigned u; } v; v.u = s << 16; return v.f;
}
union U4 { uint4 u; bf16x8 s; };

// ---------- DPP helpers ----------
__device__ __forceinline__ float dpp_red8(float x) {
  int t;
  t = __builtin_amdgcn_update_dpp(0, __float_as_int(x), 0xB1,  0xf, 0xf, true);
  x += __int_as_float(t);
  t = __builtin_amdgcn_update_dpp(0, __float_as_int(x), 0x4E,  0xf, 0xf, true);
  x += __int_as_float(t);
  t = __builtin_amdgcn_update_dpp(0, __float_as_int(x), 0x141, 0xf, 0xf, true);
  x += __int_as_float(t);
  return x;
}
__device__ __forceinline__ float dpp_red4(float x) {
  int t;
  t = __builtin_amdgcn_update_dpp(0, __float_as_int(x), 0xB1, 0xf, 0xf, true);
  x += __int_as_float(t);
  t = __builtin_amdgcn_update_dpp(0, __float_as_int(x), 0x4E, 0xf, 0xf, true);
  x += __int_as_float(t);
  return x;
}
__device__ __forceinline__ float dpp_xor1(float x) {
  return __int_as_float(__builtin_amdgcn_update_dpp(0, __float_as_int(x), 0xB1, 0xf, 0xf, true));
}

// ============================================================================
// MFMA GEMM cores.
// 64-row tile (mfma_gemm1, runs once): 4 waves x 8 col-tiles.
// 32-row tile (mfma_gemm_kvq, hot):    grid 2x313, LDS 43.5KB -> 3 blocks/CU.
// R8 change: async B prefetch (T14 issue-early/write-late) -- next phase's
// weight loads are issued into regs during the current phase's MFMA+epilogue,
// so the ~200-600cy global-load latency no longer sits between barriers.
// ============================================================================
#define GB  157   // ceil(10000/64)
#define GB2 313   // ceil(10000/32)

__device__ __forceinline__ void stage_A(const float* __restrict__ X, unsigned* sA,
                                        int rowbase, int N, int tid)
{
#pragma unroll
  for (int i = 0; i < 8; ++i) {
    int idx = tid + i * 256;
    int r = idx >> 5;
    int c4 = (idx & 31) << 2;
    int gr = rowbase + r;
    float4 v = make_float4(0.f, 0.f, 0.f, 0.f);
    if (gr < N) v = *(const float4*)(X + (size_t)gr * 128 + c4);
    sA[r * 68 + (c4 >> 1)]     = f2bf(v.x) | (f2bf(v.y) << 16);
    sA[r * 68 + (c4 >> 1) + 1] = f2bf(v.z) | (f2bf(v.w) << 16);
  }
}

__device__ __forceinline__ void stage_B(const unsigned* __restrict__ Wt, unsigned* sB, int tid)
{
#pragma unroll
  for (int i = 0; i < 8; ++i) {
    int idx = tid + i * 256;
    int n = idx >> 4;
    int k4 = (idx & 15) << 2;
    *(uint4*)&sB[n * 68 + k4] = *(const uint4*)&Wt[(size_t)idx << 2];
  }
}

// async-stage split: issue loads into regs (early) / write regs to LDS (late)
__device__ __forceinline__ void pf_B(const unsigned* __restrict__ Wt, uint4 pf[8], int tid)
{
#pragma unroll
  for (int i = 0; i < 8; ++i)
    pf[i] = *(const uint4*)&Wt[(size_t)(tid + i * 256) << 2];
}
__device__ __forceinline__ void wr_B(unsigned* sB, const uint4 pf[8], int tid)
{
#pragma unroll
  for (int i = 0; i < 8; ++i) {
    int idx = tid + i * 256;
    int n = idx >> 4;
    int k4 = (idx & 15) << 2;
    *(uint4*)&sB[n * 68 + k4] = pf[i];
  }
}

__device__ __forceinline__ void mfma_compute(const unsigned* sA, const unsigned* sB,
                                             int w, int lane, f32x4 acc[8])
{
#pragma unroll
  for (int ks = 0; ks < 4; ++ks) {
    U4 a; a.u = *(const uint4*)&sA[(w * 16 + (lane & 15)) * 68 + ks * 16 + ((lane >> 4) << 2)];
#pragma unroll
    for (int t = 0; t < 8; ++t) {
      U4 b; b.u = *(const uint4*)&sB[(t * 16 + (lane & 15)) * 68 + ks * 16 + ((lane >> 4) << 2)];
      acc[t] = __builtin_amdgcn_mfma_f32_16x16x32_bf16(a.s, b.s, acc[t], 0, 0, 0);
    }
  }
}

__device__ __forceinline__ void mfma_compute32(const unsigned* sA, const unsigned* sB,
                                               int rt, int ch, int lane, f32x4 acc[4])
{
#pragma unroll
  for (int ks = 0; ks < 4; ++ks) {
    U4 a; a.u = *(const uint4*)&sA[(rt * 16 + (lane & 15)) * 68 + ks * 16 + ((lane >> 4) << 2)];
#pragma unroll
    for (int t = 0; t < 4; ++t) {
      U4 b; b.u = *(const uint4*)&sB[((ch * 4 + t) * 16 + (lane & 15)) * 68 + ks * 16 + ((lane >> 4) << 2)];
      acc[t] = __builtin_amdgcn_mfma_f32_16x16x32_bf16(a.s, b.s, acc[t], 0, 0, 0);
    }
  }
}

// ---------- single-matrix GEMM (final layer): mode 3 = skip-blend + cat, no Y write ----------
__launch_bounds__(256, 2)
__global__ void mfma_gemm1(const float* __restrict__ X1, const float* __restrict__ X2,
                           const unsigned* __restrict__ W1t, const float* __restrict__ b1,
                           const unsigned* __restrict__ W2t, const float* __restrict__ b2,
                           float* __restrict__ Y1, float* __restrict__ Y2,
                           int nb1, int N, int mode,
                           const float* __restrict__ skip1, const float* __restrict__ skip2,
                           ushort_t* __restrict__ cat1, ushort_t* __restrict__ cat2, int catoff)
{
  __shared__ unsigned sA[64 * 68];
  __shared__ unsigned sB[128 * 68];
  const int tid = threadIdx.x;
  const bool t2 = blockIdx.x >= nb1;
  const int rowbase = (t2 ? blockIdx.x - nb1 : blockIdx.x) * 64;
  const float* X = t2 ? X2 : X1;
  const unsigned* Wt = t2 ? W2t : W1t;
  const float* bias = t2 ? b2 : b1;
  float* Y = t2 ? Y2 : Y1;
  ushort_t* cat = t2 ? cat2 : cat1;

  stage_A(X, sA, rowbase, N, tid);
  stage_B(Wt, sB, tid);
  __syncthreads();

  const int w = tid >> 6, lane = tid & 63;
  f32x4 acc[8];
#pragma unroll
  for (int t = 0; t < 8; ++t) acc[t] = (f32x4){0.f, 0.f, 0.f, 0.f};
  mfma_compute(sA, sB, w, lane, acc);

  float beta = 0.f;
  if (mode >= 2) beta = 1.0f / (1.0f + expf(-((t2 ? skip2 : skip1)[0])));
  const int cb = lane & 15;
  const int rq = (lane >> 4) << 2;
#pragma unroll
  for (int t = 0; t < 8; ++t) {
    int c = t * 16 + cb;
    float bv = bias[c];
#pragma unroll
    for (int r = 0; r < 4; ++r) {
      int row = rowbase + w * 16 + rq + r;
      float val = acc[t][r] + bv;
      if (mode == 0) {
        if (row < N) Y[(size_t)row * 128 + c] = fmaxf(val, 0.f);
      } else {
        float xo = (row < N) ? Y[(size_t)row * 128 + c] : 0.f;
        float tv = beta * val + (1.f - beta) * xo;
        if (mode == 2 && row < N) Y[(size_t)row * 128 + c] = tv;
        float nb = dpp_xor1(tv);
        if (((lane & 1) == 0) && row < N)
          *(unsigned*)(cat + (size_t)row * 256 + catoff + c) = f2bf(tv) | (f2bf(nb) << 16);
      }
    }
  }
}

// ---------- fused: GEMM0 -> pack to sA -> K/V/Q (32-row tile, async B prefetch) ----------
__launch_bounds__(256, 3)
__global__ void mfma_gemm_kvq(const float* __restrict__ A1, const float* __restrict__ A2,
                              const unsigned* __restrict__ W0T1, const float* __restrict__ b0_1,
                              const unsigned* __restrict__ W0T2, const float* __restrict__ b0_2,
                              float* __restrict__ Y1, float* __restrict__ Y2,
                              int nb1, int N, int mode,
                              const float* __restrict__ skip1, const float* __restrict__ skip2,
                              ushort_t* __restrict__ cat1, ushort_t* __restrict__ cat2, int catoff,
                              const unsigned* __restrict__ WqT1, const unsigned* __restrict__ WkT1,
                              const unsigned* __restrict__ WvT1,
                              const float* __restrict__ bq1, const float* __restrict__ bk1,
                              const float* __restrict__ bv1,
                              const unsigned* __restrict__ WqT2, const unsigned* __restrict__ WkT2,
                              const unsigned* __restrict__ WvT2,
                              const float* __restrict__ bq2, const float* __restrict__ bk2,
                              const float* __restrict__ bv2,
                              float* __restrict__ q1o, unsigned* __restrict__ kv1,
                              float* __restrict__ q2o, unsigned* __restrict__ kv2)
{
  __shared__ unsigned sA[32 * 68];
  __shared__ unsigned sB[128 * 68];
  const int tid = threadIdx.x;
  const bool t2 = blockIdx.x >= nb1;
  const int rowbase = (t2 ? blockIdx.x - nb1 : blockIdx.x) * 32;
  const float* A = t2 ? A2 : A1;
  const unsigned* W0 = t2 ? W0T2 : W0T1;
  const float* bias0 = t2 ? b0_2 : b0_1;
  float* Y = t2 ? Y2 : Y1;
  ushort_t* cat = t2 ? cat2 : cat1;

  const unsigned* Wt[3] = { t2 ? WqT2 : WqT1, t2 ? WkT2 : WkT1, t2 ? WvT2 : WvT1 };
  const float* bs[3] = { t2 ? bq2 : bq1, t2 ? bk2 : bk1, t2 ? bv2 : bv1 };
  float* qo = t2 ? q2o : q1o;
  unsigned* kvo = t2 ? kv2 : kv1;

  // stage 32-row A tile
#pragma unroll
  for (int i = 0; i < 4; ++i) {
    int idx = tid + i * 256;
    int r = idx >> 5;
    int c4 = (idx & 31) << 2;
    int gr = rowbase + r;
    float4 v = make_float4(0.f, 0.f, 0.f, 0.f);
    if (gr < N) v = *(const float4*)(A + (size_t)gr * 128 + c4);
    sA[r * 68 + (c4 >> 1)]     = f2bf(v.x) | (f2bf(v.y) << 16);
    sA[r * 68 + (c4 >> 1) + 1] = f2bf(v.z) | (f2bf(v.w) << 16);
  }
  stage_B(W0, sB, tid);
  // issue Wq loads NOW -- latency hides under GEMM0 compute+epilogue
  uint4 pf[8];
  pf_B(Wt[0], pf, tid);
  __syncthreads();

  const int w = tid >> 6, lane = tid & 63;
  const int rt = w >> 1;    // row-tile (0..1): rows rt*16 .. rt*16+15
  const int ch = w & 1;     // col-half (0..1): col-tiles ch*4 .. ch*4+3
  const int cb = lane & 15;
  const int rq = (lane >> 4) << 2;

  f32x4 acc[4];
#pragma unroll
  for (int t = 0; t < 4; ++t) acc[t] = (f32x4){0.f, 0.f, 0.f, 0.f};
  mfma_compute32(sA, sB, rt, ch, lane, acc);

  float beta = 0.f;
  if (mode == 2) beta = 1.0f / (1.0f + expf(-((t2 ? skip2 : skip1)[0])));

  // epilogue 0: finish GEMM0, write x (f32) [+ cat bf16], keep val in acc
#pragma unroll
  for (int t = 0; t < 4; ++t) {
    int c = (ch * 4 + t) * 16 + cb;
    float bv = bias0[c];
#pragma unroll
    for (int r = 0; r < 4; ++r) {
      int row = rowbase + rt * 16 + rq + r;
      float val = acc[t][r] + bv;
      if (mode == 0) {
        val = fmaxf(val, 0.f);
        if (row < N) Y[(size_t)row * 128 + c] = val;
      } else {
        float xo = (row < N) ? Y[(size_t)row * 128 + c] : 0.f;
        val = beta * val + (1.f - beta) * xo;
        if (row < N) Y[(size_t)row * 128 + c] = val;
        float nb = dpp_xor1(val);
        if (((lane & 1) == 0) && row < N)
          *(unsigned*)(cat + (size_t)row * 256 + catoff + c) = f2bf(val) | (f2bf(nb) << 16);
      }
      acc[t][r] = val;
    }
  }

  __syncthreads();   // everyone done reading sA/sB of GEMM0
  // pack new A-tile (bf16 pairs) into sA. Rows rt*16.. covered by waves
  // (rt,ch=0) cols 0-63 and (rt,ch=1) cols 64-127 -> disjoint full coverage.
#pragma unroll
  for (int t = 0; t < 4; ++t) {
#pragma unroll
    for (int r = 0; r < 4; ++r) {
      float nb = dpp_xor1(acc[t][r]);
      if ((lane & 1) == 0)
        sA[(rt * 16 + rq + r) * 68 + (((ch * 4 + t) * 16 + cb) >> 1)] = f2bf(acc[t][r]) | (f2bf(nb) << 16);
    }
  }

  for (int j = 0; j < 3; ++j) {
    __syncthreads();            // done reading sB of previous phase
    wr_B(sB, pf, tid);          // write-late: regs -> LDS
    if (j < 2) pf_B(Wt[j + 1], pf, tid);   // issue-early: next weights
    __syncthreads();            // sB (and, for j==0, packed sA) visible
#pragma unroll
    for (int t = 0; t < 4; ++t) acc[t] = (f32x4){0.f, 0.f, 0.f, 0.f};
    mfma_compute32(sA, sB, rt, ch, lane, acc);

#pragma unroll
    for (int t = 0; t < 4; ++t) {
      int c = (ch * 4 + t) * 16 + cb;
      float bv = bs[j][c];
#pragma unroll
      for (int r = 0; r < 4; ++r) {
        int row = rowbase + rt * 16 + rq + r;
        float val = acc[t][r] + bv;
        if (j == 0) {
          if (row < N) qo[(size_t)row * 128 + c] = val;
        } else {
          float nb = dpp_xor1(val);
          if (((lane & 1) == 0) && row < N) {
            unsigned pk = f2bf(val) | (f2bf(nb) << 16);
            kvo[(size_t)row * 128 + c + (j == 1 ? 0 : 1)] = pk;
          }
        }
      }
    }
  }
}

// ---------- ONE preprocessing kernel ----------
__global__ void prep(const float* W_in1, const float* W_in2,
                     const float* Wq_n1, const float* Wq_n2,
                     const float* Wa_n1, const float* Wa_n2,
                     const float* Wk_n1, const float* bk_n1,
                     const float* Wv_n1, const float* bv_n1,
                     const float* Wk_n2, const float* bk_n2,
                     const float* Wv_n2, const float* bv_n2,
                     const float* a_rel_12, const float* m_rel_12,
                     const float* a_rel_21, const float* m_rel_21,
                     unsigned* WinT1, unsigned* WinT2,
                     unsigned* WqT1, unsigned* WqT2,
                     unsigned* WaT1, unsigned* WaT2,
                     unsigned* WkT1, float* bkF1, unsigned* WvT1, float* bvF1,
                     unsigned* WkT2, float* bkF2, unsigned* WvT2, float* bvF2,
                     int* zc)
{
  const int yid = blockIdx.y;
  int idx = blockIdx.x * 256 + threadIdx.x;

  if (yid < 10) {
    if (idx >= 8192) return;
    const float* W; unsigned* Wt;
    switch (yid) {
      case 0: W = W_in1;          Wt = WinT1;        break;
      case 1: W = W_in2;          Wt = WinT2;        break;
      case 2: W = Wq_n1;          Wt = WqT1;         break;
      case 3: W = Wq_n1 + 16384;  Wt = WqT1 + 8192;  break;
      case 4: W = Wq_n2;          Wt = WqT2;         break;
      case 5: W = Wq_n2 + 16384;  Wt = WqT2 + 8192;  break;
      case 6: W = Wa_n1;          Wt = WaT1;         break;
      case 7: W = Wa_n1 + 16384;  Wt = WaT1 + 8192;  break;
      case 8: W = Wa_n2;          Wt = WaT2;         break;
      default: W = Wa_n2 + 16384; Wt = WaT2 + 8192;  break;
    }
    int n = idx & 127, kp = idx >> 7;
    float a = W[(size_t)(2 * kp) * 128 + n];
    float b = W[(size_t)(2 * kp + 1) * 128 + n];
    Wt[n * 64 + kp] = f2bf(a) | (f2bf(b) << 16);
  } else if (yid < 18) {
    int job = yid - 10;
    int l = job >> 2, m = job & 3;
    const float *W, *b, *rel; unsigned* Wt; float* bf;
    switch (m) {
      case 0:  W = Wk_n1; b = bk_n1; rel = a_rel_12; Wt = WkT1; bf = bkF1; break;
      case 1:  W = Wv_n1; b = bv_n1; rel = m_rel_12; Wt = WvT1; bf = bvF1; break;
      case 2:  W = Wk_n2; b = bk_n2; rel = a_rel_21; Wt = WkT2; bf = bkF2; break;
      default: W = Wv_n2; b = bv_n2; rel = m_rel_21; Wt = WvT2; bf = bvF2; break;
    }
    W += (size_t)l * 16384; b += l * 128; rel += (size_t)l * 2048;
    Wt += (size_t)l * 8192; bf += l * 128;
    if (idx < 8192) {
      int n = idx & 127, kp = idx >> 7;
      int h = n >> 4, e = n & 15;
      const float* rr = rel + h * 256;
      const float* s0 = W + (size_t)(2 * kp) * 128 + h * 16;
      const float* s1 = s0 + 128;
      float a0 = 0.f, a1 = 0.f;
#pragma unroll
      for (int d = 0; d < 16; ++d) {
        float rv = rr[d * 16 + e];
        a0 = fmaf(s0[d], rv, a0);
        a1 = fmaf(s1[d], rv, a1);
      }
      Wt[n * 64 + kp] = f2bf(a0) | (f2bf(a1) << 16);
    } else if (idx < 8320) {
      int n = idx - 8192;
      int h = n >> 4, e = n & 15;
      const float* rr = rel + h * 256;
      float a = 0.f;
#pragma unroll
      for (int d = 0; d < 16; ++d) a = fmaf(b[h * 16 + d], rr[d * 16 + e], a);
      bf[n] = a;
    }
  } else {
    // zero the bin-cursor block: cnt12[20] | cnt21[20] | cntF[8] (pad to 64)
    if (idx < 64) zc[idx] = 0;
  }
}

// ---------- Pass A: LDS-aggregated range partition (NO per-node global atomics) ----------
__launch_bounds__(1024)
__global__ void partition_all(const int* __restrict__ ei12, const int* __restrict__ ei21,
                              const int* __restrict__ eif,
                              int* __restrict__ cnt12, int* __restrict__ pay12,
                              int* __restrict__ cnt21, int* __restrict__ pay21,
                              int* __restrict__ cntF, int2* __restrict__ payF)
{
  __shared__ int cnt[NB2], base[NB2];
  const int t = threadIdx.x;
  const int job = blockIdx.y;
  if (job < 2) {
    const int* ei = job ? ei21 : ei12;
    int* gcnt = job ? cnt21 : cnt12;
    int* pay  = job ? pay21 : pay12;
    if (t < NB2) cnt[t] = 0;
    __syncthreads();
    int e = blockIdx.x * 1024 + t;
    const bool v = e < NE12;
    int b = 0, off = 0, w = 0;
    if (v) {
      int s = ei[e], d = ei[NE12 + e];
      b = d >> 9;
      w = ((d & 511) << 14) | s;
      off = atomicAdd(&cnt[b], 1);
    }
    __syncthreads();
    if (t < NB2) base[t] = cnt[t] ? atomicAdd(&gcnt[t], cnt[t]) : 0;
    __syncthreads();
    if (v) pay[b * BC2 + base[b] + off] = w;
  } else {
    if (t < NBIN) cnt[t] = 0;
    __syncthreads();
    int e = blockIdx.x * 1024 + t;
    const bool v = e < NEF;
    int b = 0, off = 0, m = 0, d = 0;
    if (v) {
      m = eif[e]; d = eif[NEF + e];
      b = m / BINW;
      off = atomicAdd(&cnt[b], 1);
    }
    __syncthreads();
    if (t < NBIN) base[t] = cnt[t] ? atomicAdd(&cntF[t], cnt[t]) : 0;
    __syncthreads();
    if (v) { int2 w2; w2.x = (m << 16) | d; w2.y = e; payF[(size_t)b * BCF + base[b] + off] = w2; }
  }
}

// ---------- Pass B: per-bin counting sort, keyed (dst, src-bucket) ----------
__launch_bounds__(1024)
__global__ void binsort(const int* __restrict__ cnt12, const int* __restrict__ pay12,
                        int* __restrict__ rowptr12, int* __restrict__ csr12,
                        const int* __restrict__ cnt21, const int* __restrict__ pay21,
                        int* __restrict__ rowptr21, int* __restrict__ csr21)
{
  const int wg = blockIdx.x;
  const int g = wg / NB2, b = wg % NB2;
  const int* gcnt = g ? cnt21 : cnt12;
  const int* pay  = (g ? pay21 : pay12) + (size_t)b * BC2;
  int* rowptr = g ? rowptr21 : rowptr12;
  int* csr    = g ? csr21 : csr12;
  const int t = threadIdx.x;
  const int n = gcnt[b];
  int gbase = 0;
#pragma unroll
  for (int i = 0; i < NB2; ++i) gbase += (i < b) ? gcnt[i] : 0;

  __shared__ int hist[512 * SRB];   // 10240 keys = ldst*20 + (src>>9)
  __shared__ int wsum[16];
#pragma unroll
  for (int i = 0; i < 10; ++i) hist[t + i * 1024] = 0;
  __syncthreads();
  for (int i = t; i < n; i += 1024) {
    int w = pay[i];
    atomicAdd(&hist[(w >> 14) * SRB + ((w & 16383) >> 9)], 1);
  }
  __syncthreads();
  int cv[10];
  int s = 0;
#pragma unroll
  for (int i = 0; i < 10; ++i) { cv[i] = hist[t * 10 + i]; s += cv[i]; }
  int inc = s;
#pragma unroll
  for (int off = 1; off < 64; off <<= 1) {
    int v = __shfl_up(inc, off);
    if ((t & 63) >= off) inc += v;
  }
  if ((t & 63) == 63) wsum[t >> 6] = inc;
  __syncthreads();
  if (t == 0) {
    int run = 0;
#pragma unroll
    for (int i = 0; i < 16; ++i) { int v = wsum[i]; wsum[i] = run; run += v; }
  }
  __syncthreads();
  int run = wsum[t >> 6] + (inc - s);
#pragma unroll
  for (int i = 0; i < 10; ++i) { hist[t * 10 + i] = run; run += cv[i]; }
  __syncthreads();
  if (t < 512) {
    int node = b * 512 + t;
    if (node < PN1) rowptr[node] = gbase + hist[t * SRB];
  }
  if (b == NB2 - 1 && t == 0) rowptr[PN1] = gbase + n;
  __syncthreads();
  for (int i = t; i < n; i += 1024) {
    int w = pay[i];
    int p = atomicAdd(&hist[(w >> 14) * SRB + ((w & 16383) >> 9)], 1);
    csr[gbase + p] = w & 16383;
  }
}

// ---------- readout: m-binned, XCD-resident Em slice (640 KB per XCD L2) ----------
__launch_bounds__(256)
__global__ void edge_dot_part(const int* __restrict__ cntF, const int2* __restrict__ payF,
                              const ushort_t* __restrict__ Em, const ushort_t* __restrict__ Ed,
                              float* __restrict__ y)
{
  const int part = blockIdx.x & 7;     // -> XCD (round-robin heuristic)
  const int chunk = blockIdx.x >> 3;   // 0..DCH-1
  const int lo = part * BCF;
  // Defensive clamp: never trust cntF beyond its bin capacity (rocprof
  // replay / workspace re-poison can hand this kernel garbage counts).
  int cnt = cntF[part];
  cnt = (cnt < 0) ? 0 : ((cnt > BCF) ? BCF : cnt);
  const int hi = lo + cnt;
  const int t = threadIdx.x;
  const int g = t >> 3, gl = t & 7;

  for (int k = 0;; ++k) {
    int i0 = lo + (chunk + k * DCH) * 64;
    if (i0 >= hi) break;
    int s0 = i0 + 2 * g;
    int s1 = s0 + 1;
    const bool h0 = s0 < hi, h1 = s1 < hi;
    int2 w0 = h0 ? payF[s0] : make_int2(0, 0);
    int2 w1 = h1 ? payF[s1] : w0;
    int m0 = (w0.x >> 16) & 0x3fff, d0 = w0.x & 0x3fff;
    int m1 = (w1.x >> 16) & 0x3fff, d1 = w1.x & 0x3fff;

    const uint4* A0 = (const uint4*)(Em + (size_t)m0 * 256);
    const uint4* B0 = (const uint4*)(Ed + (size_t)d0 * 256);
    const uint4* A1 = (const uint4*)(Em + (size_t)m1 * 256);
    const uint4* B1 = (const uint4*)(Ed + (size_t)d1 * 256);

    uint4 a0[4], b0[4], a1[4], b1[4];
#pragma unroll
    for (int i = 0; i < 4; ++i) { a0[i] = A0[gl + 8 * i]; b0[i] = B0[gl + 8 * i]; }
#pragma unroll
    for (int i = 0; i < 4; ++i) { a1[i] = A1[gl + 8 * i]; b1[i] = B1[gl + 8 * i]; }

    float acc0 = 0.f, acc1 = 0.f;
#pragma unroll
    for (int i = 0; i < 4; ++i) {
      uint4 a = a0[i], b = b0[i];
      acc0 = fmaf(bf2f(a.x & 0xffffu), bf2f(b.x & 0xffffu), acc0);
      acc0 = fmaf(bf2f(a.x >> 16),     bf2f(b.x >> 16),     acc0);
      acc0 = fmaf(bf2f(a.y & 0xffffu), bf2f(b.y & 0xffffu), acc0);
      acc0 = fmaf(bf2f(a.y >> 16),     bf2f(b.y >> 16),     acc0);
      acc0 = fmaf(bf2f(a.z & 0xffffu), bf2f(b.z & 0xffffu), acc0);
      acc0 = fmaf(bf2f(a.z >> 16),     bf2f(b.z >> 16),     acc0);
      acc0 = fmaf(bf2f(a.w & 0xffffu), bf2f(b.w & 0xffffu), acc0);
      acc0 = fmaf(bf2f(a.w >> 16),     bf2f(b.w >> 16),     acc0);
    }
#pragma unroll
    for (int i = 0; i < 4; ++i) {
      uint4 a = a1[i], b = b1[i];
      acc1 = fmaf(bf2f(a.x & 0xffffu), bf2f(b.x & 0xffffu), acc1);
      acc1 = fmaf(bf2f(a.x >> 16),     bf2f(b.x >> 16),     acc1);
      acc1 = fmaf(bf2f(a.y & 0xffffu), bf2f(b.y & 0xffffu), acc1);
      acc1 = fmaf(bf2f(a.y >> 16),     bf2f(b.y >> 16),     acc1);
      acc1 = fmaf(bf2f(a.z & 0xffffu), bf2f(b.z & 0xffffu), acc1);
      acc1 = fmaf(bf2f(a.z >> 16),     bf2f(b.z >> 16),     acc1);
      acc1 = fmaf(bf2f(a.w & 0xffffu), bf2f(b.w & 0xffffu), acc1);
      acc1 = fmaf(bf2f(a.w >> 16),     bf2f(b.w >> 16),     acc1);
    }
    acc0 = dpp_red8(acc0);
    acc1 = dpp_red8(acc1);
    if (gl == 0) {
      if (h0) y[w0.y] = acc0;
      if (h1) y[w1.y] = acc1;
    }
  }
}

// ---------- fused gather attention (merged both directions; src-sorted CSR) ----------
__launch_bounds__(256)
__global__ void attn_gather2(const int* __restrict__ rowptr12, const int* __restrict__ csr12,
                             const float* __restrict__ q2, const unsigned* __restrict__ kv1,
                             const float* __restrict__ pr12,
                             const int* __restrict__ rowptr21, const int* __restrict__ csr21,
                             const float* __restrict__ q1, const unsigned* __restrict__ kv2,
                             const float* __restrict__ pr21,
                             float* __restrict__ agg2, float* __restrict__ agg1)
{
  const int wid = (blockIdx.x * 256 + threadIdx.x) >> 6;
  const int lane = threadIdx.x & 63;
  const int sub = lane >> 5;
  const int sl = lane & 31;
  const bool dirB = wid >= PN2;
  const int d = __builtin_amdgcn_readfirstlane(dirB ? wid - PN2 : wid);
  const int* rowptr = dirB ? rowptr21 : rowptr12;
  const int* csr    = dirB ? csr21 : csr12;
  const float* q    = dirB ? q1 : q2;
  const unsigned* kv = dirB ? kv2 : kv1;
  const float* prel = dirB ? pr21 : pr12;
  float* agg = dirB ? agg1 : agg2;

  const int h = sl >> 2;
  const float4 qv = *(const float4*)(q + (size_t)d * 128 + 4 * sl);
  const float pr2 = prel[h] * (0.25f * 1.4426950408889634f);
  const int beg = __builtin_amdgcn_readfirstlane(rowptr[d]);
  const int end = __builtin_amdgcn_readfirstlane(rowptr[d + 1]);
  const int co = 4 * sl;

  float ssum = 0.f, a0 = 0.f, a1 = 0.f, a2 = 0.f, a3 = 0.f;

  uint4 buf[4];
#pragma unroll
  for (int j = 0; j < 4; ++j) {
    int idx = beg + 2 * j + sub;
    int s = (idx < end) ? csr[idx] : 0;
    buf[j] = *(const uint4*)(kv + (size_t)s * 128 + co);
  }

  for (int i = beg; i < end; i += 8) {
    uint4 cur[4];
#pragma unroll
    for (int j = 0; j < 4; ++j) cur[j] = buf[j];
#pragma unroll
    for (int j = 0; j < 4; ++j) {
      int idx = i + 8 + 2 * j + sub;
      int s = (idx < end) ? csr[idx] : 0;
      buf[j] = *(const uint4*)(kv + (size_t)s * 128 + co);
    }
    float p[4], ex[4];
#pragma unroll
    for (int j = 0; j < 4; ++j) {
      float t = qv.x * bf2f(cur[j].x & 0xffffu);
      t = fmaf(qv.y, bf2f(cur[j].x >> 16), t);
      t = fmaf(qv.z, bf2f(cur[j].z & 0xffffu), t);
      p[j] = fmaf(qv.w, bf2f(cur[j].z >> 16), t);
    }
#pragma unroll
    for (int j = 0; j < 4; ++j) p[j] = dpp_red4(p[j]);
#pragma unroll
    for (int j = 0; j < 4; ++j)
      ex[j] = (i + 2 * j + sub < end) ? exp2f(p[j] * pr2) : 0.f;
    ssum += (ex[0] + ex[1]) + (ex[2] + ex[3]);
#pragma unroll
    for (int j = 0; j < 4; ++j) {
      a0 = fmaf(ex[j], bf2f(cur[j].y & 0xffffu), a0);
      a1 = fmaf(ex[j], bf2f(cur[j].y >> 16),     a1);
      a2 = fmaf(ex[j], bf2f(cur[j].w & 0xffffu), a2);
      a3 = fmaf(ex[j], bf2f(cur[j].w >> 16),     a3);
    }
  }

  ssum += __shfl_xor(ssum, 32);
  a0 += __shfl_xor(a0, 32);
  a1 += __shfl_xor(a1, 32);
  a2 += __shfl_xor(a2, 32);
  a3 += __shfl_xor(a3, 32);

  if (sub == 0) {
    const float inv = 1.0f / (ssum + 1e-16f);
    float o0 = a0 * inv, o1 = a1 * inv, o2 = a2 * inv, o3 = a3 * inv;
    o0 = 0.5f * o0 * (1.f + erff(o0 * 0.70710678118654752f));
    o1 = 0.5f * o1 * (1.f + erff(o1 * 0.70710678118654752f));
    o2 = 0.5f * o2 * (1.f + erff(o2 * 0.70710678118654752f));
    o3 = 0.5f * o3 * (1.f + erff(o3 * 0.70710678118654752f));
    float4 out; out.x = o0; out.y = o1; out.z = o2; out.w = o3;
    *(float4*)(agg + (size_t)d * 128 + co) = out;
  }
}

// ---------- launch ----------
extern "C" void kernel_launch(void* const* d_in, const int* in_sizes, int n_in,
                              void* d_out, int out_size, void* d_ws, size_t ws_size,
                              hipStream_t stream)
{
  const float* x_n1  = (const float*)d_in[0];
  const float* x_n2  = (const float*)d_in[1];
  const float* W_in1 = (const float*)d_in[2];
  const float* b_in1 = (const float*)d_in[3];
  const float* W_in2 = (const float*)d_in[4];
  const float* b_in2 = (const float*)d_in[5];
  const float* Wk_n1 = (const float*)d_in[6];
  const float* bk_n1 = (const float*)d_in[7];
  const float* Wq_n1 = (const float*)d_in[8];
  const float* bq_n1 = (const float*)d_in[9];
  const float* Wv_n1 = (const float*)d_in[10];
  const float* bv_n1 = (const float*)d_in[11];
  const float* Wa_n1 = (const float*)d_in[12];
  const float* ba_n1 = (const float*)d_in[13];
  const float* skip_n1 = (const float*)d_in[14];
  const float* Wk_n2 = (const float*)d_in[15];
  const float* bk_n2 = (const float*)d_in[16];
  const float* Wq_n2 = (const float*)d_in[17];
  const float* bq_n2 = (const float*)d_in[18];
  const float* Wv_n2 = (const float*)d_in[19];
  const float* bv_n2 = (const float*)d_in[20];
  const float* Wa_n2 = (const float*)d_in[21];
  const float* ba_n2 = (const float*)d_in[22];
  const float* skip_n2 = (const float*)d_in[23];
  const float* a_rel_12 = (const float*)d_in[24];
  const float* m_rel_12 = (const float*)d_in[25];
  const float* p_rel_12 = (const float*)d_in[26];
  const float* a_rel_21 = (const float*)d_in[27];
  const float* m_rel_21 = (const float*)d_in[28];
  const float* p_rel_21 = (const float*)d_in[29];
  const int*   ei_12 = (const int*)d_in[30];
  const int*   ei_21 = (const int*)d_in[31];
  const int*   edge_index = (const int*)d_in[32];
  float* y = (float*)d_out;

  // ---- workspace carve-up (float units) ----
  const size_t NF = (size_t)PN1 * 128;
  float* ws = (float*)d_ws;
  float* x1   = ws + 0 * NF;
  float* x2   = ws + 1 * NF;
  float* q1   = ws + 2 * NF;
  float* q2   = ws + 3 * NF;
  float* agg1 = ws + 4 * NF;
  float* agg2 = ws + 5 * NF;
  unsigned* kv1 = (unsigned*)(ws + 6 * NF);
  unsigned* kv2 = (unsigned*)(ws + 7 * NF);
  ushort_t* Em  = (ushort_t*)(ws + 8 * NF);
  ushort_t* Ed  = (ushort_t*)(ws + 8 * NF + 1280000);
  unsigned* wb = (unsigned*)(ws + 8 * NF + 2560000);
  unsigned* WkT1 = wb;                     float* bkF1 = (float*)(wb + 16384);
  unsigned* WvT1 = wb + 16640;             float* bvF1 = (float*)(wb + 33024);
  unsigned* WkT2 = wb + 33280;             float* bkF2 = (float*)(wb + 49664);
  unsigned* WvT2 = wb + 49920;             float* bvF2 = (float*)(wb + 66304);
  unsigned* WinT1 = wb + 66560;
  unsigned* WinT2 = wb + 74752;
  unsigned* WqT1  = wb + 82944;
  unsigned* WqT2  = wb + 99328;
  unsigned* WaT1  = wb + 115712;
  unsigned* WaT2  = wb + 132096;
  int* ip = (int*)(wb + 148480);
  int* rowptr12 = ip;                 // DL
  int* rowptr21 = ip + DL;            // DL
  int* zc       = ip + 2 * DL;        // 64 zeroed ints: cnt12|cnt21|cntF
  int* cnt12 = zc;
  int* cnt21 = zc + 20;
  int* cntF  = zc + 40;
  int* csr12 = ip + 2 * DL + 64;      // NE12
  int* csr21 = csr12 + NE12;          // NE21
  int* pay12 = csr21 + NE21;          // NB2*BC2
  int* pay21 = pay12 + NB2 * BC2;     // NB2*BC2
  int2* payF = (int2*)(pay21 + NB2 * BC2);   // NBIN*BCF int2

  // ---- one preprocessing dispatch ----
  prep<<<dim3(33, 19), 256, 0, stream>>>(
      W_in1, W_in2, Wq_n1, Wq_n2, Wa_n1, Wa_n2,
      Wk_n1, bk_n1, Wv_n1, bv_n1, Wk_n2, bk_n2, Wv_n2, bv_n2,
      a_rel_12, m_rel_12, a_rel_21, m_rel_21,
      WinT1, WinT2, WqT1, WqT2, WaT1, WaT2,
      WkT1, bkF1, WvT1, bvF1, WkT2, bkF2, WvT2, bvF2, zc);

  // ---- graph build: partition (pass A) + keyed counting sort (pass B) ----
  const int PAB = (NEF + 1023) / 1024;   // 489 (covers all three edge sets)
  partition_all<<<dim3(PAB, 3), 1024, 0, stream>>>(
      ei_12, ei_21, edge_index,
      cnt12, pay12, cnt21, pay21, cntF, payF);
  binsort<<<2 * NB2, 1024, 0, stream>>>(
      cnt12, pay12, rowptr12, csr12,
      cnt21, pay21, rowptr21, csr21);

  // ---- input projections + relu, fused with layer-0 K/V/Q (32-row tiles) ----
  mfma_gemm_kvq<<<2 * GB2, 256, 0, stream>>>(
      x_n1, x_n2, WinT1, b_in1, WinT2, b_in2,
      x1, x2, GB2, PN1, 0, nullptr, nullptr, nullptr, nullptr, 0,
      WqT1, WkT1, WvT1, bq_n1, bkF1, bvF1,
      WqT2, WkT2, WvT2, bq_n2, bkF2, bvF2,
      q1, kv1, q2, kv2);

  // ---- layer 0 attention (merged directions) ----
  attn_gather2<<<(2 * PN1) / 4, 256, 0, stream>>>(
      rowptr12, csr12, q2, kv1, p_rel_12,
      rowptr21, csr21, q1, kv2, p_rel_21,
      agg2, agg1);

  // ---- layer 0 output GEMM + blend + cat, fused with layer-1 K/V/Q ----
  mfma_gemm_kvq<<<2 * GB2, 256, 0, stream>>>(
      agg1, agg2, WaT1, ba_n1, WaT2, ba_n2,
      x1, x2, GB2, PN1, 2, skip_n1, skip_n2, Em, Ed, 0,
      WqT1 + 8192, WkT1 + 8192, WvT1 + 8192, bq_n1 + 128, bkF1 + 128, bvF1 + 128,
      WqT2 + 8192, WkT2 + 8192, WvT2 + 8192, bq_n2 + 128, bkF2 + 128, bvF2 + 128,
      q1, kv1, q2, kv2);

  // ---- layer 1 attention ----
  attn_gather2<<<(2 * PN1) / 4, 256, 0, stream>>>(
      rowptr12, csr12, q2, kv1, p_rel_12 + NH,
      rowptr21, csr21, q1, kv2, p_rel_21 + NH,
      agg2, agg1);

  // ---- layer 1 output GEMM: cat only (x is dead afterwards -> mode 3, no Y write) ----
  mfma_gemm1<<<2 * GB, 256, 0, stream>>>(
      agg1, agg2, WaT1 + 8192, ba_n1 + 128, WaT2 + 8192, ba_n2 + 128,
      x1, x2, GB, PN1, 3, skip_n1 + 1, skip_n2 + 1, Em, Ed, 128);

  // ---- readout: m-binned ----
  edge_dot_part<<<NBIN * DCH, 256, 0, stream>>>(cntF, payF, Em, Ed, y);
}

// Round 10
// 312.821 us; speedup vs baseline: 1.1153x; 1.1153x over previous
//
#include <hip/hip_runtime.h>
#include <cstdint>
#include <cstddef>

typedef unsigned short ushort_t;
typedef __attribute__((ext_vector_type(8))) short bf16x8;
typedef __attribute__((ext_vector_type(4))) float f32x4;

// Problem constants
#define PN1   10000
#define PN2   10000
#define NH    8
#define NLAY  2
#define NE12  320000
#define NE21  320000
#define NEF   500000
#define DL    10016   // padded per-node array stride
#define NBIN  8       // edge_dot m-bins (one per XCD)
#define BINW  1250    // m rows per bin
#define BCF   65536   // capacity per edge_dot bin (expected ~62.5K)
#define DCH   256     // chunks per part in edge_dot_part
#define NB2   20      // CSR dst-range bins per graph (width 512)
#define BC2   20480   // capacity per CSR bin (expected <=16384)
#define SRB   20      // src buckets per dst (width 512) for drift-aligned gathers

// ---------- bf16 helpers (RNE) ----------
__device__ __forceinline__ unsigned f2bf(float f) {
  union { float f; unsigned u; } v; v.f = f;
  return (v.u + 0x7FFFu + ((v.u >> 16) & 1u)) >> 16;
}
__device__ __forceinline__ float bf2f(unsigned s) {
  union { float f; unsigned u; } v; v.u = s << 16; return v.f;
}
union U4 { uint4 u; bf16x8 s; };

// ---------- DPP helpers ----------
__device__ __forceinline__ float dpp_red8(float x) {
  int t;
  t = __builtin_amdgcn_update_dpp(0, __float_as_int(x), 0xB1,  0xf, 0xf, true);
  x += __int_as_float(t);
  t = __builtin_amdgcn_update_dpp(0, __float_as_int(x), 0x4E,  0xf, 0xf, true);
  x += __int_as_float(t);
  t = __builtin_amdgcn_update_dpp(0, __float_as_int(x), 0x141, 0xf, 0xf, true);
  x += __int_as_float(t);
  return x;
}
__device__ __forceinline__ float dpp_red4(float x) {
  int t;
  t = __builtin_amdgcn_update_dpp(0, __float_as_int(x), 0xB1, 0xf, 0xf, true);
  x += __int_as_float(t);
  t = __builtin_amdgcn_update_dpp(0, __float_as_int(x), 0x4E, 0xf, 0xf, true);
  x += __int_as_float(t);
  return x;
}
__device__ __forceinline__ float dpp_xor1(float x) {
  return __int_as_float(__builtin_amdgcn_update_dpp(0, __float_as_int(x), 0xB1, 0xf, 0xf, true));
}

// ============================================================================
// MFMA GEMM cores.
// 64-row tile (mfma_gemm1, runs once): 4 waves x 8 col-tiles.
// 32-row tile (mfma_gemm_kvq, hot):    grid 2x313, LDS 43.5KB -> 3 blocks/CU,
//   waves split (row-tile = w>>1, col-half = w&1) -> ~2.5 waves/SIMD.
// NOTE (R9 lesson): do NOT register-prefetch the next phase's weights here --
// a uint4[8] held live across mfma+epilogue spills to scratch (+60MB traffic,
// +32us). Cross-block TLP at 3 blocks/CU already hides the stage_B latency.
// ============================================================================
#define GB  157   // ceil(10000/64)
#define GB2 313   // ceil(10000/32)

__device__ __forceinline__ void stage_A(const float* __restrict__ X, unsigned* sA,
                                        int rowbase, int N, int tid)
{
#pragma unroll
  for (int i = 0; i < 8; ++i) {
    int idx = tid + i * 256;
    int r = idx >> 5;
    int c4 = (idx & 31) << 2;
    int gr = rowbase + r;
    float4 v = make_float4(0.f, 0.f, 0.f, 0.f);
    if (gr < N) v = *(const float4*)(X + (size_t)gr * 128 + c4);
    sA[r * 68 + (c4 >> 1)]     = f2bf(v.x) | (f2bf(v.y) << 16);
    sA[r * 68 + (c4 >> 1) + 1] = f2bf(v.z) | (f2bf(v.w) << 16);
  }
}

__device__ __forceinline__ void stage_B(const unsigned* __restrict__ Wt, unsigned* sB, int tid)
{
#pragma unroll
  for (int i = 0; i < 8; ++i) {
    int idx = tid + i * 256;
    int n = idx >> 4;
    int k4 = (idx & 15) << 2;
    *(uint4*)&sB[n * 68 + k4] = *(const uint4*)&Wt[(size_t)idx << 2];
  }
}

__device__ __forceinline__ void mfma_compute(const unsigned* sA, const unsigned* sB,
                                             int w, int lane, f32x4 acc[8])
{
#pragma unroll
  for (int ks = 0; ks < 4; ++ks) {
    U4 a; a.u = *(const uint4*)&sA[(w * 16 + (lane & 15)) * 68 + ks * 16 + ((lane >> 4) << 2)];
#pragma unroll
    for (int t = 0; t < 8; ++t) {
      U4 b; b.u = *(const uint4*)&sB[(t * 16 + (lane & 15)) * 68 + ks * 16 + ((lane >> 4) << 2)];
      acc[t] = __builtin_amdgcn_mfma_f32_16x16x32_bf16(a.s, b.s, acc[t], 0, 0, 0);
    }
  }
}

__device__ __forceinline__ void mfma_compute32(const unsigned* sA, const unsigned* sB,
                                               int rt, int ch, int lane, f32x4 acc[4])
{
#pragma unroll
  for (int ks = 0; ks < 4; ++ks) {
    U4 a; a.u = *(const uint4*)&sA[(rt * 16 + (lane & 15)) * 68 + ks * 16 + ((lane >> 4) << 2)];
#pragma unroll
    for (int t = 0; t < 4; ++t) {
      U4 b; b.u = *(const uint4*)&sB[((ch * 4 + t) * 16 + (lane & 15)) * 68 + ks * 16 + ((lane >> 4) << 2)];
      acc[t] = __builtin_amdgcn_mfma_f32_16x16x32_bf16(a.s, b.s, acc[t], 0, 0, 0);
    }
  }
}

// ---------- single-matrix GEMM (final layer): mode 3 = skip-blend + cat, no Y write ----------
__launch_bounds__(256, 2)
__global__ void mfma_gemm1(const float* __restrict__ X1, const float* __restrict__ X2,
                           const unsigned* __restrict__ W1t, const float* __restrict__ b1,
                           const unsigned* __restrict__ W2t, const float* __restrict__ b2,
                           float* __restrict__ Y1, float* __restrict__ Y2,
                           int nb1, int N, int mode,
                           const float* __restrict__ skip1, const float* __restrict__ skip2,
                           ushort_t* __restrict__ cat1, ushort_t* __restrict__ cat2, int catoff)
{
  __shared__ unsigned sA[64 * 68];
  __shared__ unsigned sB[128 * 68];
  const int tid = threadIdx.x;
  const bool t2 = blockIdx.x >= nb1;
  const int rowbase = (t2 ? blockIdx.x - nb1 : blockIdx.x) * 64;
  const float* X = t2 ? X2 : X1;
  const unsigned* Wt = t2 ? W2t : W1t;
  const float* bias = t2 ? b2 : b1;
  float* Y = t2 ? Y2 : Y1;
  ushort_t* cat = t2 ? cat2 : cat1;

  stage_A(X, sA, rowbase, N, tid);
  stage_B(Wt, sB, tid);
  __syncthreads();

  const int w = tid >> 6, lane = tid & 63;
  f32x4 acc[8];
#pragma unroll
  for (int t = 0; t < 8; ++t) acc[t] = (f32x4){0.f, 0.f, 0.f, 0.f};
  mfma_compute(sA, sB, w, lane, acc);

  float beta = 0.f;
  if (mode >= 2) beta = 1.0f / (1.0f + expf(-((t2 ? skip2 : skip1)[0])));
  const int cb = lane & 15;
  const int rq = (lane >> 4) << 2;
#pragma unroll
  for (int t = 0; t < 8; ++t) {
    int c = t * 16 + cb;
    float bv = bias[c];
#pragma unroll
    for (int r = 0; r < 4; ++r) {
      int row = rowbase + w * 16 + rq + r;
      float val = acc[t][r] + bv;
      if (mode == 0) {
        if (row < N) Y[(size_t)row * 128 + c] = fmaxf(val, 0.f);
      } else {
        float xo = (row < N) ? Y[(size_t)row * 128 + c] : 0.f;
        float tv = beta * val + (1.f - beta) * xo;
        if (mode == 2 && row < N) Y[(size_t)row * 128 + c] = tv;
        float nb = dpp_xor1(tv);
        if (((lane & 1) == 0) && row < N)
          *(unsigned*)(cat + (size_t)row * 256 + catoff + c) = f2bf(tv) | (f2bf(nb) << 16);
      }
    }
  }
}

// ---------- fused: GEMM0 -> pack to sA -> K/V/Q (32-row tile, 3 blocks/CU) ----------
__launch_bounds__(256, 3)
__global__ void mfma_gemm_kvq(const float* __restrict__ A1, const float* __restrict__ A2,
                              const unsigned* __restrict__ W0T1, const float* __restrict__ b0_1,
                              const unsigned* __restrict__ W0T2, const float* __restrict__ b0_2,
                              float* __restrict__ Y1, float* __restrict__ Y2,
                              int nb1, int N, int mode,
                              const float* __restrict__ skip1, const float* __restrict__ skip2,
                              ushort_t* __restrict__ cat1, ushort_t* __restrict__ cat2, int catoff,
                              const unsigned* __restrict__ WqT1, const unsigned* __restrict__ WkT1,
                              const unsigned* __restrict__ WvT1,
                              const float* __restrict__ bq1, const float* __restrict__ bk1,
                              const float* __restrict__ bv1,
                              const unsigned* __restrict__ WqT2, const unsigned* __restrict__ WkT2,
                              const unsigned* __restrict__ WvT2,
                              const float* __restrict__ bq2, const float* __restrict__ bk2,
                              const float* __restrict__ bv2,
                              float* __restrict__ q1o, unsigned* __restrict__ kv1,
                              float* __restrict__ q2o, unsigned* __restrict__ kv2)
{
  __shared__ unsigned sA[32 * 68];
  __shared__ unsigned sB[128 * 68];
  const int tid = threadIdx.x;
  const bool t2 = blockIdx.x >= nb1;
  const int rowbase = (t2 ? blockIdx.x - nb1 : blockIdx.x) * 32;
  const float* A = t2 ? A2 : A1;
  const unsigned* W0 = t2 ? W0T2 : W0T1;
  const float* bias0 = t2 ? b0_2 : b0_1;
  float* Y = t2 ? Y2 : Y1;
  ushort_t* cat = t2 ? cat2 : cat1;

  // stage 32-row A tile
#pragma unroll
  for (int i = 0; i < 4; ++i) {
    int idx = tid + i * 256;
    int r = idx >> 5;
    int c4 = (idx & 31) << 2;
    int gr = rowbase + r;
    float4 v = make_float4(0.f, 0.f, 0.f, 0.f);
    if (gr < N) v = *(const float4*)(A + (size_t)gr * 128 + c4);
    sA[r * 68 + (c4 >> 1)]     = f2bf(v.x) | (f2bf(v.y) << 16);
    sA[r * 68 + (c4 >> 1) + 1] = f2bf(v.z) | (f2bf(v.w) << 16);
  }
  stage_B(W0, sB, tid);
  __syncthreads();

  const int w = tid >> 6, lane = tid & 63;
  const int rt = w >> 1;    // row-tile (0..1): rows rt*16 .. rt*16+15
  const int ch = w & 1;     // col-half (0..1): col-tiles ch*4 .. ch*4+3
  const int cb = lane & 15;
  const int rq = (lane >> 4) << 2;

  f32x4 acc[4];
#pragma unroll
  for (int t = 0; t < 4; ++t) acc[t] = (f32x4){0.f, 0.f, 0.f, 0.f};
  mfma_compute32(sA, sB, rt, ch, lane, acc);

  float beta = 0.f;
  if (mode == 2) beta = 1.0f / (1.0f + expf(-((t2 ? skip2 : skip1)[0])));

  // epilogue 0: finish GEMM0, write x (f32) [+ cat bf16], keep val in acc
#pragma unroll
  for (int t = 0; t < 4; ++t) {
    int c = (ch * 4 + t) * 16 + cb;
    float bv = bias0[c];
#pragma unroll
    for (int r = 0; r < 4; ++r) {
      int row = rowbase + rt * 16 + rq + r;
      float val = acc[t][r] + bv;
      if (mode == 0) {
        val = fmaxf(val, 0.f);
        if (row < N) Y[(size_t)row * 128 + c] = val;
      } else {
        float xo = (row < N) ? Y[(size_t)row * 128 + c] : 0.f;
        val = beta * val + (1.f - beta) * xo;
        if (row < N) Y[(size_t)row * 128 + c] = val;
        float nb = dpp_xor1(val);
        if (((lane & 1) == 0) && row < N)
          *(unsigned*)(cat + (size_t)row * 256 + catoff + c) = f2bf(val) | (f2bf(nb) << 16);
      }
      acc[t][r] = val;
    }
  }

  __syncthreads();   // everyone done reading sA/sB of GEMM0
  // pack new A-tile (bf16 pairs) into sA. Rows rt*16.. covered by waves
  // (rt,ch=0) cols 0-63 and (rt,ch=1) cols 64-127 -> disjoint full coverage.
#pragma unroll
  for (int t = 0; t < 4; ++t) {
#pragma unroll
    for (int r = 0; r < 4; ++r) {
      float nb = dpp_xor1(acc[t][r]);
      if ((lane & 1) == 0)
        sA[(rt * 16 + rq + r) * 68 + (((ch * 4 + t) * 16 + cb) >> 1)] = f2bf(acc[t][r]) | (f2bf(nb) << 16);
    }
  }

  const unsigned* Wt[3] = { t2 ? WqT2 : WqT1, t2 ? WkT2 : WkT1, t2 ? WvT2 : WvT1 };
  const float* bs[3] = { t2 ? bq2 : bq1, t2 ? bk2 : bk1, t2 ? bv2 : bv1 };
  float* qo = t2 ? q2o : q1o;
  unsigned* kvo = t2 ? kv2 : kv1;

  for (int j = 0; j < 3; ++j) {
    __syncthreads();
    stage_B(Wt[j], sB, tid);
    __syncthreads();
#pragma unroll
    for (int t = 0; t < 4; ++t) acc[t] = (f32x4){0.f, 0.f, 0.f, 0.f};
    mfma_compute32(sA, sB, rt, ch, lane, acc);

#pragma unroll
    for (int t = 0; t < 4; ++t) {
      int c = (ch * 4 + t) * 16 + cb;
      float bv = bs[j][c];
#pragma unroll
      for (int r = 0; r < 4; ++r) {
        int row = rowbase + rt * 16 + rq + r;
        float val = acc[t][r] + bv;
        if (j == 0) {
          if (row < N) qo[(size_t)row * 128 + c] = val;
        } else {
          float nb = dpp_xor1(val);
          if (((lane & 1) == 0) && row < N) {
            unsigned pk = f2bf(val) | (f2bf(nb) << 16);
            kvo[(size_t)row * 128 + c + (j == 1 ? 0 : 1)] = pk;
          }
        }
      }
    }
  }
}

// ---------- ONE preprocessing kernel ----------
__global__ void prep(const float* W_in1, const float* W_in2,
                     const float* Wq_n1, const float* Wq_n2,
                     const float* Wa_n1, const float* Wa_n2,
                     const float* Wk_n1, const float* bk_n1,
                     const float* Wv_n1, const float* bv_n1,
                     const float* Wk_n2, const float* bk_n2,
                     const float* Wv_n2, const float* bv_n2,
                     const float* a_rel_12, const float* m_rel_12,
                     const float* a_rel_21, const float* m_rel_21,
                     unsigned* WinT1, unsigned* WinT2,
                     unsigned* WqT1, unsigned* WqT2,
                     unsigned* WaT1, unsigned* WaT2,
                     unsigned* WkT1, float* bkF1, unsigned* WvT1, float* bvF1,
                     unsigned* WkT2, float* bkF2, unsigned* WvT2, float* bvF2,
                     int* zc)
{
  const int yid = blockIdx.y;
  int idx = blockIdx.x * 256 + threadIdx.x;

  if (yid < 10) {
    if (idx >= 8192) return;
    const float* W; unsigned* Wt;
    switch (yid) {
      case 0: W = W_in1;          Wt = WinT1;        break;
      case 1: W = W_in2;          Wt = WinT2;        break;
      case 2: W = Wq_n1;          Wt = WqT1;         break;
      case 3: W = Wq_n1 + 16384;  Wt = WqT1 + 8192;  break;
      case 4: W = Wq_n2;          Wt = WqT2;         break;
      case 5: W = Wq_n2 + 16384;  Wt = WqT2 + 8192;  break;
      case 6: W = Wa_n1;          Wt = WaT1;         break;
      case 7: W = Wa_n1 + 16384;  Wt = WaT1 + 8192;  break;
      case 8: W = Wa_n2;          Wt = WaT2;         break;
      default: W = Wa_n2 + 16384; Wt = WaT2 + 8192;  break;
    }
    int n = idx & 127, kp = idx >> 7;
    float a = W[(size_t)(2 * kp) * 128 + n];
    float b = W[(size_t)(2 * kp + 1) * 128 + n];
    Wt[n * 64 + kp] = f2bf(a) | (f2bf(b) << 16);
  } else if (yid < 18) {
    int job = yid - 10;
    int l = job >> 2, m = job & 3;
    const float *W, *b, *rel; unsigned* Wt; float* bf;
    switch (m) {
      case 0:  W = Wk_n1; b = bk_n1; rel = a_rel_12; Wt = WkT1; bf = bkF1; break;
      case 1:  W = Wv_n1; b = bv_n1; rel = m_rel_12; Wt = WvT1; bf = bvF1; break;
      case 2:  W = Wk_n2; b = bk_n2; rel = a_rel_21; Wt = WkT2; bf = bkF2; break;
      default: W = Wv_n2; b = bv_n2; rel = m_rel_21; Wt = WvT2; bf = bvF2; break;
    }
    W += (size_t)l * 16384; b += l * 128; rel += (size_t)l * 2048;
    Wt += (size_t)l * 8192; bf += l * 128;
    if (idx < 8192) {
      int n = idx & 127, kp = idx >> 7;
      int h = n >> 4, e = n & 15;
      const float* rr = rel + h * 256;
      const float* s0 = W + (size_t)(2 * kp) * 128 + h * 16;
      const float* s1 = s0 + 128;
      float a0 = 0.f, a1 = 0.f;
#pragma unroll
      for (int d = 0; d < 16; ++d) {
        float rv = rr[d * 16 + e];
        a0 = fmaf(s0[d], rv, a0);
        a1 = fmaf(s1[d], rv, a1);
      }
      Wt[n * 64 + kp] = f2bf(a0) | (f2bf(a1) << 16);
    } else if (idx < 8320) {
      int n = idx - 8192;
      int h = n >> 4, e = n & 15;
      const float* rr = rel + h * 256;
      float a = 0.f;
#pragma unroll
      for (int d = 0; d < 16; ++d) a = fmaf(b[h * 16 + d], rr[d * 16 + e], a);
      bf[n] = a;
    }
  } else {
    // zero the bin-cursor block: cnt12[20] | cnt21[20] | cntF[8] (pad to 64)
    if (idx < 64) zc[idx] = 0;
  }
}

// ---------- Pass A: LDS-aggregated range partition (NO per-node global atomics) ----------
__launch_bounds__(1024)
__global__ void partition_all(const int* __restrict__ ei12, const int* __restrict__ ei21,
                              const int* __restrict__ eif,
                              int* __restrict__ cnt12, int* __restrict__ pay12,
                              int* __restrict__ cnt21, int* __restrict__ pay21,
                              int* __restrict__ cntF, int2* __restrict__ payF)
{
  __shared__ int cnt[NB2], base[NB2];
  const int t = threadIdx.x;
  const int job = blockIdx.y;
  if (job < 2) {
    const int* ei = job ? ei21 : ei12;
    int* gcnt = job ? cnt21 : cnt12;
    int* pay  = job ? pay21 : pay12;
    if (t < NB2) cnt[t] = 0;
    __syncthreads();
    int e = blockIdx.x * 1024 + t;
    const bool v = e < NE12;
    int b = 0, off = 0, w = 0;
    if (v) {
      int s = ei[e], d = ei[NE12 + e];
      b = d >> 9;
      w = ((d & 511) << 14) | s;
      off = atomicAdd(&cnt[b], 1);
    }
    __syncthreads();
    if (t < NB2) base[t] = cnt[t] ? atomicAdd(&gcnt[t], cnt[t]) : 0;
    __syncthreads();
    if (v) pay[b * BC2 + base[b] + off] = w;
  } else {
    if (t < NBIN) cnt[t] = 0;
    __syncthreads();
    int e = blockIdx.x * 1024 + t;
    const bool v = e < NEF;
    int b = 0, off = 0, m = 0, d = 0;
    if (v) {
      m = eif[e]; d = eif[NEF + e];
      b = m / BINW;
      off = atomicAdd(&cnt[b], 1);
    }
    __syncthreads();
    if (t < NBIN) base[t] = cnt[t] ? atomicAdd(&cntF[t], cnt[t]) : 0;
    __syncthreads();
    if (v) { int2 w2; w2.x = (m << 16) | d; w2.y = e; payF[(size_t)b * BCF + base[b] + off] = w2; }
  }
}

// ---------- Pass B: per-bin counting sort, keyed (dst, src-bucket) ----------
__launch_bounds__(1024)
__global__ void binsort(const int* __restrict__ cnt12, const int* __restrict__ pay12,
                        int* __restrict__ rowptr12, int* __restrict__ csr12,
                        const int* __restrict__ cnt21, const int* __restrict__ pay21,
                        int* __restrict__ rowptr21, int* __restrict__ csr21)
{
  const int wg = blockIdx.x;
  const int g = wg / NB2, b = wg % NB2;
  const int* gcnt = g ? cnt21 : cnt12;
  const int* pay  = (g ? pay21 : pay12) + (size_t)b * BC2;
  int* rowptr = g ? rowptr21 : rowptr12;
  int* csr    = g ? csr21 : csr12;
  const int t = threadIdx.x;
  const int n = gcnt[b];
  int gbase = 0;
#pragma unroll
  for (int i = 0; i < NB2; ++i) gbase += (i < b) ? gcnt[i] : 0;

  __shared__ int hist[512 * SRB];   // 10240 keys = ldst*20 + (src>>9)
  __shared__ int wsum[16];
#pragma unroll
  for (int i = 0; i < 10; ++i) hist[t + i * 1024] = 0;
  __syncthreads();
  for (int i = t; i < n; i += 1024) {
    int w = pay[i];
    atomicAdd(&hist[(w >> 14) * SRB + ((w & 16383) >> 9)], 1);
  }
  __syncthreads();
  int cv[10];
  int s = 0;
#pragma unroll
  for (int i = 0; i < 10; ++i) { cv[i] = hist[t * 10 + i]; s += cv[i]; }
  int inc = s;
#pragma unroll
  for (int off = 1; off < 64; off <<= 1) {
    int v = __shfl_up(inc, off);
    if ((t & 63) >= off) inc += v;
  }
  if ((t & 63) == 63) wsum[t >> 6] = inc;
  __syncthreads();
  if (t == 0) {
    int run = 0;
#pragma unroll
    for (int i = 0; i < 16; ++i) { int v = wsum[i]; wsum[i] = run; run += v; }
  }
  __syncthreads();
  int run = wsum[t >> 6] + (inc - s);
#pragma unroll
  for (int i = 0; i < 10; ++i) { hist[t * 10 + i] = run; run += cv[i]; }
  __syncthreads();
  if (t < 512) {
    int node = b * 512 + t;
    if (node < PN1) rowptr[node] = gbase + hist[t * SRB];
  }
  if (b == NB2 - 1 && t == 0) rowptr[PN1] = gbase + n;
  __syncthreads();
  for (int i = t; i < n; i += 1024) {
    int w = pay[i];
    int p = atomicAdd(&hist[(w >> 14) * SRB + ((w & 16383) >> 9)], 1);
    csr[gbase + p] = w & 16383;
  }
}

// ---------- readout: m-binned, XCD-resident Em slice (640 KB per XCD L2) ----------
__launch_bounds__(256)
__global__ void edge_dot_part(const int* __restrict__ cntF, const int2* __restrict__ payF,
                              const ushort_t* __restrict__ Em, const ushort_t* __restrict__ Ed,
                              float* __restrict__ y)
{
  const int part = blockIdx.x & 7;     // -> XCD (round-robin heuristic)
  const int chunk = blockIdx.x >> 3;   // 0..DCH-1
  const int lo = part * BCF;
  // Defensive clamp: never trust cntF beyond its bin capacity (rocprof
  // replay / workspace re-poison can hand this kernel garbage counts).
  int cnt = cntF[part];
  cnt = (cnt < 0) ? 0 : ((cnt > BCF) ? BCF : cnt);
  const int hi = lo + cnt;
  const int t = threadIdx.x;
  const int g = t >> 3, gl = t & 7;

  for (int k = 0;; ++k) {
    int i0 = lo + (chunk + k * DCH) * 64;
    if (i0 >= hi) break;
    int s0 = i0 + 2 * g;
    int s1 = s0 + 1;
    const bool h0 = s0 < hi, h1 = s1 < hi;
    int2 w0 = h0 ? payF[s0] : make_int2(0, 0);
    int2 w1 = h1 ? payF[s1] : w0;
    int m0 = (w0.x >> 16) & 0x3fff, d0 = w0.x & 0x3fff;
    int m1 = (w1.x >> 16) & 0x3fff, d1 = w1.x & 0x3fff;

    const uint4* A0 = (const uint4*)(Em + (size_t)m0 * 256);
    const uint4* B0 = (const uint4*)(Ed + (size_t)d0 * 256);
    const uint4* A1 = (const uint4*)(Em + (size_t)m1 * 256);
    const uint4* B1 = (const uint4*)(Ed + (size_t)d1 * 256);

    uint4 a0[4], b0[4], a1[4], b1[4];
#pragma unroll
    for (int i = 0; i < 4; ++i) { a0[i] = A0[gl + 8 * i]; b0[i] = B0[gl + 8 * i]; }
#pragma unroll
    for (int i = 0; i < 4; ++i) { a1[i] = A1[gl + 8 * i]; b1[i] = B1[gl + 8 * i]; }

    float acc0 = 0.f, acc1 = 0.f;
#pragma unroll
    for (int i = 0; i < 4; ++i) {
      uint4 a = a0[i], b = b0[i];
      acc0 = fmaf(bf2f(a.x & 0xffffu), bf2f(b.x & 0xffffu), acc0);
      acc0 = fmaf(bf2f(a.x >> 16),     bf2f(b.x >> 16),     acc0);
      acc0 = fmaf(bf2f(a.y & 0xffffu), bf2f(b.y & 0xffffu), acc0);
      acc0 = fmaf(bf2f(a.y >> 16),     bf2f(b.y >> 16),     acc0);
      acc0 = fmaf(bf2f(a.z & 0xffffu), bf2f(b.z & 0xffffu), acc0);
      acc0 = fmaf(bf2f(a.z >> 16),     bf2f(b.z >> 16),     acc0);
      acc0 = fmaf(bf2f(a.w & 0xffffu), bf2f(b.w & 0xffffu), acc0);
      acc0 = fmaf(bf2f(a.w >> 16),     bf2f(b.w >> 16),     acc0);
    }
#pragma unroll
    for (int i = 0; i < 4; ++i) {
      uint4 a = a1[i], b = b1[i];
      acc1 = fmaf(bf2f(a.x & 0xffffu), bf2f(b.x & 0xffffu), acc1);
      acc1 = fmaf(bf2f(a.x >> 16),     bf2f(b.x >> 16),     acc1);
      acc1 = fmaf(bf2f(a.y & 0xffffu), bf2f(b.y & 0xffffu), acc1);
      acc1 = fmaf(bf2f(a.y >> 16),     bf2f(b.y >> 16),     acc1);
      acc1 = fmaf(bf2f(a.z & 0xffffu), bf2f(b.z & 0xffffu), acc1);
      acc1 = fmaf(bf2f(a.z >> 16),     bf2f(b.z >> 16),     acc1);
      acc1 = fmaf(bf2f(a.w & 0xffffu), bf2f(b.w & 0xffffu), acc1);
      acc1 = fmaf(bf2f(a.w >> 16),     bf2f(b.w >> 16),     acc1);
    }
    acc0 = dpp_red8(acc0);
    acc1 = dpp_red8(acc1);
    if (gl == 0) {
      if (h0) y[w0.y] = acc0;
      if (h1) y[w1.y] = acc1;
    }
  }
}

// ---------- fused gather attention (merged both directions; src-sorted CSR) ----------
__launch_bounds__(256)
__global__ void attn_gather2(const int* __restrict__ rowptr12, const int* __restrict__ csr12,
                             const float* __restrict__ q2, const unsigned* __restrict__ kv1,
                             const float* __restrict__ pr12,
                             const int* __restrict__ rowptr21, const int* __restrict__ csr21,
                             const float* __restrict__ q1, const unsigned* __restrict__ kv2,
                             const float* __restrict__ pr21,
                             float* __restrict__ agg2, float* __restrict__ agg1)
{
  const int wid = (blockIdx.x * 256 + threadIdx.x) >> 6;
  const int lane = threadIdx.x & 63;
  const int sub = lane >> 5;
  const int sl = lane & 31;
  const bool dirB = wid >= PN2;
  const int d = __builtin_amdgcn_readfirstlane(dirB ? wid - PN2 : wid);
  const int* rowptr = dirB ? rowptr21 : rowptr12;
  const int* csr    = dirB ? csr21 : csr12;
  const float* q    = dirB ? q1 : q2;
  const unsigned* kv = dirB ? kv2 : kv1;
  const float* prel = dirB ? pr21 : pr12;
  float* agg = dirB ? agg1 : agg2;

  const int h = sl >> 2;
  const float4 qv = *(const float4*)(q + (size_t)d * 128 + 4 * sl);
  const float pr2 = prel[h] * (0.25f * 1.4426950408889634f);
  const int beg = __builtin_amdgcn_readfirstlane(rowptr[d]);
  const int end = __builtin_amdgcn_readfirstlane(rowptr[d + 1]);
  const int co = 4 * sl;

  float ssum = 0.f, a0 = 0.f, a1 = 0.f, a2 = 0.f, a3 = 0.f;

  uint4 buf[4];
#pragma unroll
  for (int j = 0; j < 4; ++j) {
    int idx = beg + 2 * j + sub;
    int s = (idx < end) ? csr[idx] : 0;
    buf[j] = *(const uint4*)(kv + (size_t)s * 128 + co);
  }

  for (int i = beg; i < end; i += 8) {
    uint4 cur[4];
#pragma unroll
    for (int j = 0; j < 4; ++j) cur[j] = buf[j];
#pragma unroll
    for (int j = 0; j < 4; ++j) {
      int idx = i + 8 + 2 * j + sub;
      int s = (idx < end) ? csr[idx] : 0;
      buf[j] = *(const uint4*)(kv + (size_t)s * 128 + co);
    }
    float p[4], ex[4];
#pragma unroll
    for (int j = 0; j < 4; ++j) {
      float t = qv.x * bf2f(cur[j].x & 0xffffu);
      t = fmaf(qv.y, bf2f(cur[j].x >> 16), t);
      t = fmaf(qv.z, bf2f(cur[j].z & 0xffffu), t);
      p[j] = fmaf(qv.w, bf2f(cur[j].z >> 16), t);
    }
#pragma unroll
    for (int j = 0; j < 4; ++j) p[j] = dpp_red4(p[j]);
#pragma unroll
    for (int j = 0; j < 4; ++j)
      ex[j] = (i + 2 * j + sub < end) ? exp2f(p[j] * pr2) : 0.f;
    ssum += (ex[0] + ex[1]) + (ex[2] + ex[3]);
#pragma unroll
    for (int j = 0; j < 4; ++j) {
      a0 = fmaf(ex[j], bf2f(cur[j].y & 0xffffu), a0);
      a1 = fmaf(ex[j], bf2f(cur[j].y >> 16),     a1);
      a2 = fmaf(ex[j], bf2f(cur[j].w & 0xffffu), a2);
      a3 = fmaf(ex[j], bf2f(cur[j].w >> 16),     a3);
    }
  }

  ssum += __shfl_xor(ssum, 32);
  a0 += __shfl_xor(a0, 32);
  a1 += __shfl_xor(a1, 32);
  a2 += __shfl_xor(a2, 32);
  a3 += __shfl_xor(a3, 32);

  if (sub == 0) {
    const float inv = 1.0f / (ssum + 1e-16f);
    float o0 = a0 * inv, o1 = a1 * inv, o2 = a2 * inv, o3 = a3 * inv;
    o0 = 0.5f * o0 * (1.f + erff(o0 * 0.70710678118654752f));
    o1 = 0.5f * o1 * (1.f + erff(o1 * 0.70710678118654752f));
    o2 = 0.5f * o2 * (1.f + erff(o2 * 0.70710678118654752f));
    o3 = 0.5f * o3 * (1.f + erff(o3 * 0.70710678118654752f));
    float4 out; out.x = o0; out.y = o1; out.z = o2; out.w = o3;
    *(float4*)(agg + (size_t)d * 128 + co) = out;
  }
}

// ---------- launch ----------
extern "C" void kernel_launch(void* const* d_in, const int* in_sizes, int n_in,
                              void* d_out, int out_size, void* d_ws, size_t ws_size,
                              hipStream_t stream)
{
  const float* x_n1  = (const float*)d_in[0];
  const float* x_n2  = (const float*)d_in[1];
  const float* W_in1 = (const float*)d_in[2];
  const float* b_in1 = (const float*)d_in[3];
  const float* W_in2 = (const float*)d_in[4];
  const float* b_in2 = (const float*)d_in[5];
  const float* Wk_n1 = (const float*)d_in[6];
  const float* bk_n1 = (const float*)d_in[7];
  const float* Wq_n1 = (const float*)d_in[8];
  const float* bq_n1 = (const float*)d_in[9];
  const float* Wv_n1 = (const float*)d_in[10];
  const float* bv_n1 = (const float*)d_in[11];
  const float* Wa_n1 = (const float*)d_in[12];
  const float* ba_n1 = (const float*)d_in[13];
  const float* skip_n1 = (const float*)d_in[14];
  const float* Wk_n2 = (const float*)d_in[15];
  const float* bk_n2 = (const float*)d_in[16];
  const float* Wq_n2 = (const float*)d_in[17];
  const float* bq_n2 = (const float*)d_in[18];
  const float* Wv_n2 = (const float*)d_in[19];
  const float* bv_n2 = (const float*)d_in[20];
  const float* Wa_n2 = (const float*)d_in[21];
  const float* ba_n2 = (const float*)d_in[22];
  const float* skip_n2 = (const float*)d_in[23];
  const float* a_rel_12 = (const float*)d_in[24];
  const float* m_rel_12 = (const float*)d_in[25];
  const float* p_rel_12 = (const float*)d_in[26];
  const float* a_rel_21 = (const float*)d_in[27];
  const float* m_rel_21 = (const float*)d_in[28];
  const float* p_rel_21 = (const float*)d_in[29];
  const int*   ei_12 = (const int*)d_in[30];
  const int*   ei_21 = (const int*)d_in[31];
  const int*   edge_index = (const int*)d_in[32];
  float* y = (float*)d_out;

  // ---- workspace carve-up (float units) ----
  const size_t NF = (size_t)PN1 * 128;
  float* ws = (float*)d_ws;
  float* x1   = ws + 0 * NF;
  float* x2   = ws + 1 * NF;
  float* q1   = ws + 2 * NF;
  float* q2   = ws + 3 * NF;
  float* agg1 = ws + 4 * NF;
  float* agg2 = ws + 5 * NF;
  unsigned* kv1 = (unsigned*)(ws + 6 * NF);
  unsigned* kv2 = (unsigned*)(ws + 7 * NF);
  ushort_t* Em  = (ushort_t*)(ws + 8 * NF);
  ushort_t* Ed  = (ushort_t*)(ws + 8 * NF + 1280000);
  unsigned* wb = (unsigned*)(ws + 8 * NF + 2560000);
  unsigned* WkT1 = wb;                     float* bkF1 = (float*)(wb + 16384);
  unsigned* WvT1 = wb + 16640;             float* bvF1 = (float*)(wb + 33024);
  unsigned* WkT2 = wb + 33280;             float* bkF2 = (float*)(wb + 49664);
  unsigned* WvT2 = wb + 49920;             float* bvF2 = (float*)(wb + 66304);
  unsigned* WinT1 = wb + 66560;
  unsigned* WinT2 = wb + 74752;
  unsigned* WqT1  = wb + 82944;
  unsigned* WqT2  = wb + 99328;
  unsigned* WaT1  = wb + 115712;
  unsigned* WaT2  = wb + 132096;
  int* ip = (int*)(wb + 148480);
  int* rowptr12 = ip;                 // DL
  int* rowptr21 = ip + DL;            // DL
  int* zc       = ip + 2 * DL;        // 64 zeroed ints: cnt12|cnt21|cntF
  int* cnt12 = zc;
  int* cnt21 = zc + 20;
  int* cntF  = zc + 40;
  int* csr12 = ip + 2 * DL + 64;      // NE12
  int* csr21 = csr12 + NE12;          // NE21
  int* pay12 = csr21 + NE21;          // NB2*BC2
  int* pay21 = pay12 + NB2 * BC2;     // NB2*BC2
  int2* payF = (int2*)(pay21 + NB2 * BC2);   // NBIN*BCF int2

  // ---- one preprocessing dispatch ----
  prep<<<dim3(33, 19), 256, 0, stream>>>(
      W_in1, W_in2, Wq_n1, Wq_n2, Wa_n1, Wa_n2,
      Wk_n1, bk_n1, Wv_n1, bv_n1, Wk_n2, bk_n2, Wv_n2, bv_n2,
      a_rel_12, m_rel_12, a_rel_21, m_rel_21,
      WinT1, WinT2, WqT1, WqT2, WaT1, WaT2,
      WkT1, bkF1, WvT1, bvF1, WkT2, bkF2, WvT2, bvF2, zc);

  // ---- graph build: partition (pass A) + keyed counting sort (pass B) ----
  const int PAB = (NEF + 1023) / 1024;   // 489 (covers all three edge sets)
  partition_all<<<dim3(PAB, 3), 1024, 0, stream>>>(
      ei_12, ei_21, edge_index,
      cnt12, pay12, cnt21, pay21, cntF, payF);
  binsort<<<2 * NB2, 1024, 0, stream>>>(
      cnt12, pay12, rowptr12, csr12,
      cnt21, pay21, rowptr21, csr21);

  // ---- input projections + relu, fused with layer-0 K/V/Q (32-row tiles) ----
  mfma_gemm_kvq<<<2 * GB2, 256, 0, stream>>>(
      x_n1, x_n2, WinT1, b_in1, WinT2, b_in2,
      x1, x2, GB2, PN1, 0, nullptr, nullptr, nullptr, nullptr, 0,
      WqT1, WkT1, WvT1, bq_n1, bkF1, bvF1,
      WqT2, WkT2, WvT2, bq_n2, bkF2, bvF2,
      q1, kv1, q2, kv2);

  // ---- layer 0 attention (merged directions) ----
  attn_gather2<<<(2 * PN1) / 4, 256, 0, stream>>>(
      rowptr12, csr12, q2, kv1, p_rel_12,
      rowptr21, csr21, q1, kv2, p_rel_21,
      agg2, agg1);

  // ---- layer 0 output GEMM + blend + cat, fused with layer-1 K/V/Q ----
  mfma_gemm_kvq<<<2 * GB2, 256, 0, stream>>>(
      agg1, agg2, WaT1, ba_n1, WaT2, ba_n2,
      x1, x2, GB2, PN1, 2, skip_n1, skip_n2, Em, Ed, 0,
      WqT1 + 8192, WkT1 + 8192, WvT1 + 8192, bq_n1 + 128, bkF1 + 128, bvF1 + 128,
      WqT2 + 8192, WkT2 + 8192, WvT2 + 8192, bq_n2 + 128, bkF2 + 128, bvF2 + 128,
      q1, kv1, q2, kv2);

  // ---- layer 1 attention ----
  attn_gather2<<<(2 * PN1) / 4, 256, 0, stream>>>(
      rowptr12, csr12, q2, kv1, p_rel_12 + NH,
      rowptr21, csr21, q1, kv2, p_rel_21 + NH,
      agg2, agg1);

  // ---- layer 1 output GEMM: cat only (x is dead afterwards -> mode 3, no Y write) ----
  mfma_gemm1<<<2 * GB, 256, 0, stream>>>(
      agg1, agg2, WaT1 + 8192, ba_n1 + 128, WaT2 + 8192, ba_n2 + 128,
      x1, x2, GB, PN1, 3, skip_n1 + 1, skip_n2 + 1, Em, Ed, 128);

  // ---- readout: m-binned ----
  edge_dot_part<<<NBIN * DCH, 256, 0, stream>>>(cntF, payF, Em, Ed, y);
}